// Round 8
// baseline (1299.118 us; speedup 1.0000x reference)
//
#include <hip/hip_runtime.h>

#define B_  8
#define N_  4096
#define S_  1024
#define K_  64
#define CF_ 128
#define M_  (B_*S_*K_)   // 524288 rows per layer

typedef __attribute__((ext_vector_type(8))) short bshort8;
typedef __attribute__((ext_vector_type(4))) float f32x4;
typedef __attribute__((ext_vector_type(4))) int   i32x4;
typedef __attribute__((ext_vector_type(2))) float f32x2;
typedef __attribute__((ext_vector_type(4))) unsigned short us4;

__device__ __forceinline__ unsigned short f2bf(float f){
  unsigned int u = __float_as_uint(f);
  u = u + 0x7FFFu + ((u >> 16) & 1u);      // RTNE
  return (unsigned short)(u >> 16);
}
__device__ __forceinline__ float bf2f(unsigned short h){
  return __uint_as_float(((unsigned int)h) << 16);
}

// ---------------------------------------------------------------------------
// prep: transpose (blocks 0..4095) + weight prep (blocks 4096..4159)
// ---------------------------------------------------------------------------
__global__ __launch_bounds__(256) void prep_kernel(const float* __restrict__ f,
                                                   const float* __restrict__ W1,
                                                   const float* __restrict__ W2,
                                                   const float* __restrict__ W3,
                                                   unsigned short* __restrict__ ft,
                                                   unsigned short* __restrict__ Wt1,
                                                   unsigned short* __restrict__ Wt2,
                                                   unsigned short* __restrict__ Wt3){
  __shared__ float tile[32][33];
  const int blk = blockIdx.x;
  if (blk < 4096){
    int nt = blk & 127, ct = (blk>>7)&3, b = blk>>9;
    int tx = threadIdx.x & 31, ty = threadIdx.x >> 5;
#pragma unroll
    for (int r=0; r<32; r+=8)
      tile[ty+r][tx] = f[((size_t)(b*128 + ct*32 + ty + r))*4096 + nt*32 + tx];
    __syncthreads();
#pragma unroll
    for (int r=0; r<32; r+=8){
      int n = nt*32 + ty + r, cc = ct*32 + tx;
      ft[((size_t)b*4096 + n)*128 + cc] = f2bf(tile[tx][ty+r]);
    }
  } else {
    int t = (blk-4096)*256 + threadIdx.x;
    int stride = 64*256;
    for (int idx=t; idx<128*160; idx+=stride){
      int n = idx/160, k = idx-(idx/160)*160;
      float v = 0.f;
      if (k < 128) v = W1[(k+3)*128 + n];
      else if (k < 131) v = W1[(k-128)*128 + n];
      Wt1[idx] = f2bf(v);
    }
    for (int idx=t; idx<128*128; idx+=stride){
      int n = idx>>7, k = idx&127;
      Wt2[idx] = f2bf(W2[k*128+n]);
    }
    for (int idx=t; idx<256*128; idx+=stride){
      int n = idx>>7, k = idx&127;
      Wt3[idx] = f2bf(W3[k*256+n]);
    }
  }
}

// ---------------------------------------------------------------------------
// pgemm: P = featT x W1_feat (f32 out), standalone (r10 version) — runs
// BEFORE fps so fps keeps its uncontended floor (r11 merge cost 28us).
// ---------------------------------------------------------------------------
__global__ __launch_bounds__(256,2) void pgemm_kernel(const unsigned short* __restrict__ featT,
                                                      const unsigned short* __restrict__ Wt1,
                                                      float* __restrict__ P){
  __shared__ alignas(16) unsigned short At[128*40];
  __shared__ alignas(16) unsigned short Bt[128*40];
  const int t = threadIdx.x, blk = blockIdx.x;     // 256 blocks
  const size_t rowBase = (size_t)blk*128;
  const int lane = t&63, wave = t>>6;
  const int wm = wave>>1, wn = wave&1;
  const int lrow = lane&15, quad = lane>>4;
  f32x4 acc[4][4];
  const f32x4 z4 = {0.f,0.f,0.f,0.f};
#pragma unroll
  for (int i=0;i<4;++i)
#pragma unroll
    for (int j=0;j<4;++j) acc[i][j]=z4;
  for (int ch=0; ch<4; ++ch){
    __syncthreads();
#pragma unroll
    for (int half=0; half<2; ++half){
      int sl = t + half*256; int r = sl>>2, p = sl&3;
      *(bshort8*)&At[r*40+p*8] = *(const bshort8*)(featT + (rowBase + r)*CF_ + ch*32 + p*8);
      *(bshort8*)&Bt[r*40+p*8] = *(const bshort8*)(Wt1 + r*160 + ch*32 + p*8);
    }
    __syncthreads();
    bshort8 af[4], bfr[4];
#pragma unroll
    for (int mt=0; mt<4; ++mt) af[mt]  = *(const bshort8*)&At[(wm*64+mt*16+lrow)*40 + quad*8];
#pragma unroll
    for (int nt=0; nt<4; ++nt) bfr[nt] = *(const bshort8*)&Bt[(wn*64+nt*16+lrow)*40 + quad*8];
#pragma unroll
    for (int mt=0; mt<4; ++mt)
#pragma unroll
      for (int nt=0; nt<4; ++nt)
        acc[mt][nt] = __builtin_amdgcn_mfma_f32_16x16x32_bf16(af[mt], bfr[nt], acc[mt][nt], 0,0,0);
  }
#pragma unroll
  for (int mt=0; mt<4; ++mt)
#pragma unroll
    for (int nt=0; nt<4; ++nt)
#pragma unroll
      for (int r=0; r<4; ++r){
        int row = wm*64 + mt*16 + quad*4 + r;
        int col = wn*64 + nt*16 + lrow;
        P[(rowBase + row)*128 + col] = acc[mt][nt][r];
      }
}

// ---------------------------------------------------------------------------
// FPS: r7/r10 inner-loop body EXACTLY (serial scan + dependent sx[farthest]
// read — every instruction-level variant lost: serial=793, prefetch=843,
// tree=947). STRUCTURAL change under test: 512 threads (8 waves = 2 per
// SIMD, was 1/SIMD) so each wave's ~1350 stall cyc/iter can hide under the
// other wave's issue. Each thread owns 8 points (was 16); cross-wave reduce
// is 8 partials via named-scalar pairwise tree (assoc. (max,min-idx) —
// bit-identical to reference argmax).
// ---------------------------------------------------------------------------
#define DPP_PAIR_STEP(CTRL)                                                     \
  {                                                                             \
    int _vi = __builtin_amdgcn_update_dpp(__float_as_int(best), __float_as_int(best), (CTRL), 0xF, 0xF, false); \
    int _ii = __builtin_amdgcn_update_dpp(bidx, bidx, (CTRL), 0xF, 0xF, false); \
    float _ov = __int_as_float(_vi);                                            \
    bool _tk = (_ov > best) || (_ov == best && _ii < bidx);                     \
    best = _tk ? _ov : best;                                                    \
    bidx = _tk ? _ii : bidx;                                                    \
  }

__global__ __launch_bounds__(512) void fps_kernel(const float* __restrict__ xyz,
                                                  float* __restrict__ nx_out,
                                                  float* __restrict__ nx_ws){
#pragma clang fp contract(off)
  __shared__ float sx[N_], sy[N_], sz[N_];
  __shared__ int   sidx[S_];
  __shared__ alignas(16) float redv[2][8];
  __shared__ alignas(16) int   redi[2][8];
  const int b = blockIdx.x, t = threadIdx.x;
  const int lane = t & 63, w = t >> 6;     // w in 0..7
  const float* xb = xyz + (size_t)b*N_*3;
  f32x2 px[4], py[4], pz[4], dist[4];
#pragma unroll
  for (int j=0;j<4;++j){
    int i0 = (2*j)*512 + t, i1 = (2*j+1)*512 + t;
    float x0=xb[i0*3+0], y0=xb[i0*3+1], z0=xb[i0*3+2];
    float x1=xb[i1*3+0], y1=xb[i1*3+1], z1=xb[i1*3+2];
    px[j] = (f32x2){x0,x1}; py[j] = (f32x2){y0,y1}; pz[j] = (f32x2){z0,z1};
    dist[j] = (f32x2){1e10f,1e10f};
    sx[i0]=x0; sy[i0]=y0; sz[i0]=z0;
    sx[i1]=x1; sy[i1]=y1; sz[i1]=z1;
  }
  __syncthreads();
  int farthest = 0;
  for (int it=0; it<S_; ++it){
    if (t==0) sidx[it] = farthest;
    float cx = sx[farthest], cy = sy[farthest], cz = sz[farthest];
    f32x2 cx2 = (f32x2){cx,cx}, cy2 = (f32x2){cy,cy}, cz2 = (f32x2){cz,cz};
    float best = -1.0f; int bidx = 0;
#pragma unroll
    for (int j=0;j<4;++j){
      f32x2 dx = px[j] - cx2;
      f32x2 dy = py[j] - cy2;
      f32x2 dz = pz[j] - cz2;
      f32x2 d  = (dx*dx + dy*dy) + dz*dz;
      f32x2 nd;
      nd.x = fminf(dist[j].x, d.x);
      nd.y = fminf(dist[j].y, d.y);
      dist[j] = nd;
      bool tk0 = nd.x > best;
      best = tk0 ? nd.x : best;
      bidx = tk0 ? ((2*j)*512 + t) : bidx;
      bool tk1 = nd.y > best;
      best = tk1 ? nd.y : best;
      bidx = tk1 ? ((2*j+1)*512 + t) : bidx;
    }
    DPP_PAIR_STEP(0xB1);
    DPP_PAIR_STEP(0x4E);
    DPP_PAIR_STEP(0x124);
    DPP_PAIR_STEP(0x128);
    DPP_PAIR_STEP(0x142);
    DPP_PAIR_STEP(0x143);
    const int buf = it & 1;
    if (lane == 63){ redv[buf][w] = best; redi[buf][w] = bidx; }
    __syncthreads();
    f32x4 vvl = *(const f32x4*)&redv[buf][0];
    f32x4 vvh = *(const f32x4*)&redv[buf][4];
    i32x4 ivl = *(const i32x4*)&redi[buf][0];
    i32x4 ivh = *(const i32x4*)&redi[buf][4];
    // pairwise tree over 8 partials, named scalars only (no arrays — r2 lesson)
    float va = vvl[0]; int ia = ivl[0];
    { bool tk = (vvl[1] > va) || (vvl[1] == va && ivl[1] < ia); va = tk?vvl[1]:va; ia = tk?ivl[1]:ia; }
    float vb = vvl[2]; int ib = ivl[2];
    { bool tk = (vvl[3] > vb) || (vvl[3] == vb && ivl[3] < ib); vb = tk?vvl[3]:vb; ib = tk?ivl[3]:ib; }
    float vc = vvh[0]; int ic = ivh[0];
    { bool tk = (vvh[1] > vc) || (vvh[1] == vc && ivh[1] < ic); vc = tk?vvh[1]:vc; ic = tk?ivh[1]:ic; }
    float vd = vvh[2]; int idd = ivh[2];
    { bool tk = (vvh[3] > vd) || (vvh[3] == vd && ivh[3] < idd); vd = tk?vvh[3]:vd; idd = tk?ivh[3]:idd; }
    { bool tk = (vb > va) || (vb == va && ib < ia); va = tk?vb:va; ia = tk?ib:ia; }
    { bool tk = (vd > vc) || (vd == vc && idd < ic); vc = tk?vd:vc; ic = tk?idd:ic; }
    { bool tk = (vc > va) || (vc == va && ic < ia); va = tk?vc:va; ia = tk?ic:ia; }
    farthest = ia;
  }
  __syncthreads();
  for (int i=t; i<S_; i+=512){
    int id = sidx[i];
    size_t base = (size_t)(b*S_+i)*3;
    float vx=sx[id], vy=sy[id], vz=sz[id];
    nx_out[base+0]=vx; nx_out[base+1]=vy; nx_out[base+2]=vz;
    nx_ws[base+0]=vx;  nx_ws[base+1]=vy;  nx_ws[base+2]=vz;
  }
}

// ---------------------------------------------------------------------------
// qbp + y1 column stats fused (r11-exact).
// ---------------------------------------------------------------------------
__global__ __launch_bounds__(256) void qbp_y1_kernel(const float* __restrict__ xyz,
                                                     const float* __restrict__ nx,
                                                     const float* __restrict__ P,
                                                     const float* __restrict__ W1,
                                                     int* __restrict__ gi,
                                                     float* __restrict__ slots){
  __shared__ int giW[4][64];
  __shared__ alignas(16) float dxL[4][64][4];
  __shared__ float sLDS[128], s2LDS[128];
  const int t = threadIdx.x;
  const int lane = t & 63, w = t >> 6;
  if (t < 128){ sLDS[t]=0.f; s2LDS[t]=0.f; }
  __syncthreads();
  const int wid = blockIdx.x*4 + w;
  const int b = wid >> 10, s = wid & 1023;
  const float* xb = xyz + (size_t)b*N_*3;
  {
    const double R2 = 0.2*0.2;
    const float* c  = nx + (size_t)(b*S_+s)*3;
    double cx=(double)c[0], cy=(double)c[1], cz=(double)c[2];
    double cc = cx*cx + cy*cy + cz*cz;
    int* g = gi + (size_t)(b*S_+s)*K_;
    int count = 0, first = -1;
    for (int ch=0; ch<64 && count<K_; ++ch){
      int i = ch*64 + lane;
      double x = (double)xb[i*3+0], y = (double)xb[i*3+1], z = (double)xb[i*3+2];
      double e  = cx*x + cy*y + cz*z;
      double pp = x*x + y*y + z*z;
      double d  = -2.0*e + cc + pp;
      bool keep = !(d > R2);
      unsigned long long bal = __ballot(keep);
      int pos = count + __builtin_popcountll(bal & ((1ull<<lane)-1ull));
      if (keep && pos < K_){ g[pos] = i; giW[w][pos] = i; }
      if (first < 0 && bal) first = ch*64 + (int)__builtin_ctzll(bal);
      count += __builtin_popcountll(bal);
    }
    if (count < K_){
      int p = count + lane;
      if (p < K_){ g[p] = first; giW[w][p] = first; }
    }
    int i = giW[w][lane];
    const float* pp = xyz + ((size_t)b*N_ + i)*3;
    const float* qq = nx  + (size_t)(b*S_ + s)*3;
    dxL[w][lane][0] = __fsub_rn(pp[0],qq[0]);
    dxL[w][lane][1] = __fsub_rn(pp[1],qq[1]);
    dxL[w][lane][2] = __fsub_rn(pp[2],qq[2]);
  }
  {
    const int cq = lane*2;
    f32x2 w0 = *(const f32x2*)(W1 + cq);
    f32x2 w1v = *(const f32x2*)(W1 + 128 + cq);
    f32x2 w2 = *(const f32x2*)(W1 + 256 + cq);
    f32x2 sA = {0,0}, s2A = {0,0};
#pragma unroll 4
    for (int r=0; r<64; ++r){
      int pi = giW[w][r];
      f32x2 p = *(const f32x2*)(P + ((size_t)b*N_ + pi)*128 + cq);
      float dx = dxL[w][r][0], dy = dxL[w][r][1], dz = dxL[w][r][2];
      f32x2 y;
#pragma unroll
      for (int e=0;e<2;++e)
        y[e] = fmaf(dz, w2[e], fmaf(dy, w1v[e], fmaf(dx, w0[e], p[e])));
      sA.x += y.x; sA.y += y.y;
      s2A.x = fmaf(y.x,y.x,s2A.x); s2A.y = fmaf(y.y,y.y,s2A.y);
    }
    atomicAdd(&sLDS[cq],    sA.x);  atomicAdd(&sLDS[cq+1],  sA.y);
    atomicAdd(&s2LDS[cq],   s2A.x); atomicAdd(&s2LDS[cq+1], s2A.y);
  }
  __syncthreads();
  if (t < 128){
    int slot = blockIdx.x & 63;
    atomicAdd(&slots[(slot*128+t)*2+0], sLDS[t]);
    atomicAdd(&slots[(slot*128+t)*2+1], s2LDS[t]);
  }
}

// ---------------------------------------------------------------------------
// mm_fused: PHASE 2 computes sums2 (+ optional raw-y2 bf16 store for STOREY2);
// PHASE 3 (fallback, r11-exact) recomputes y1->GEMM2 then GEMM3.
// ---------------------------------------------------------------------------
template<int PHASE, bool STOREY2>
__global__ __launch_bounds__(256,2) void mm_fused(
    const float* __restrict__ P,
    const float* __restrict__ W1,
    const unsigned short* __restrict__ Wt2,
    const unsigned short* __restrict__ Wt3,
    const int* __restrict__ gi,
    const float* __restrict__ xyz,
    const float* __restrict__ nxyz,
    const float* __restrict__ ss1,
    const float* __restrict__ ss2,
    float* __restrict__ slots,
    float* __restrict__ minv,
    float* __restrict__ maxv,
    unsigned short* __restrict__ y2out)
{
  __shared__ alignas(16) unsigned short Bt[2][128*40];
  __shared__ alignas(16) unsigned short Y[128*136];
  __shared__ int giL[128];
  __shared__ alignas(16) float dxL[128][4];
  __shared__ alignas(16) float w0L[128], w1L[128], w2L[128];

  const int t = threadIdx.x;
  const int mblk = blockIdx.x;
  const int b = mblk >> 9;
  const int lane = t&63, wave = t>>6;
  const int wm = wave>>1, wn = wave&1;
  const int lrow = lane&15, quad = lane>>4;
  const int slot = mblk & 63;

  if (t<128){
    int i = gi[(size_t)mblk*128 + t];
    giL[t] = i;
    int s = ((mblk*128 + t) >> 6) & 1023;
    const float* pp = xyz  + ((size_t)b*N_ + i)*3;
    const float* qq = nxyz + (size_t)(b*S_ + s)*3;
    dxL[t][0] = __fsub_rn(pp[0],qq[0]);
    dxL[t][1] = __fsub_rn(pp[1],qq[1]);
    dxL[t][2] = __fsub_rn(pp[2],qq[2]);
    w0L[t] = W1[t]; w1L[t] = W1[128+t]; w2L[t] = W1[256+t];
  }
  __syncthreads();

  // ---- y1 + BN1 + ReLU -> Y ----
  {
    const int rgrp = t>>5, cq = (t&31)*4;
    f32x4 w0 = *(const f32x4*)&w0L[cq];
    f32x4 w1 = *(const f32x4*)&w1L[cq];
    f32x4 w2 = *(const f32x4*)&w2L[cq];
    f32x4 a1v = *(const f32x4*)(ss1 + cq);
    f32x4 b1v = *(const f32x4*)(ss1 + 128 + cq);
#pragma unroll
    for (int g=0; g<16; ++g){
      int r = g*8 + rgrp;
      int pi = giL[r];
      f32x4 p = *(const f32x4*)(P + ((size_t)b*N_ + pi)*128 + cq);
      float dx = dxL[r][0], dy = dxL[r][1], dz = dxL[r][2];
      f32x4 y;
#pragma unroll
      for (int e=0;e<4;++e)
        y[e] = fmaf(dz, w2[e], fmaf(dy, w1[e], fmaf(dx, w0[e], p[e])));
      us4 zz;
#pragma unroll
      for (int e=0;e<4;++e)
        zz[e] = f2bf(fmaxf(fmaf(y[e], a1v[e], b1v[e]), 0.f));
      *(us4*)&Y[r*136 + cq] = zz;
    }
  }

  f32x4 acc[4][4];
  const f32x4 z4 = {0.f,0.f,0.f,0.f};
#pragma unroll
  for (int i=0;i<4;++i)
#pragma unroll
    for (int j=0;j<4;++j) acc[i][j]=z4;

  // ---------------- GEMM2 (dbuf): A = Y (z1), K=128 ----------------
  {
    bshort8 bV[2];
#pragma unroll
    for (int half=0; half<2; ++half){
      int sl = t + half*256; int r = sl>>2, p = sl&3;
      bV[half] = *(const bshort8*)(Wt2 + r*128 + p*8);
    }
#pragma unroll
    for (int half=0; half<2; ++half){
      int sl = t + half*256; int r = sl>>2, p = sl&3;
      *(bshort8*)&Bt[1][r*40+p*8] = bV[half];
    }
    for (int ch=0; ch<4; ++ch){
      const int cur = (ch & 1) ^ 1;
      __syncthreads();
      bshort8 af[4], bfr[4];
#pragma unroll
      for (int mt=0; mt<4; ++mt) af[mt]  = *(const bshort8*)&Y[(wm*64+mt*16+lrow)*136 + ch*32 + quad*8];
#pragma unroll
      for (int nt=0; nt<4; ++nt) bfr[nt] = *(const bshort8*)&Bt[cur][(wn*64+nt*16+lrow)*40 + quad*8];
      if (ch < 3){
#pragma unroll
        for (int half=0; half<2; ++half){
          int sl = t + half*256; int r = sl>>2, p = sl&3;
          bV[half] = *(const bshort8*)(Wt2 + r*128 + (ch+1)*32 + p*8);
        }
      }
#pragma unroll
      for (int mt=0; mt<4; ++mt)
#pragma unroll
        for (int nt=0; nt<4; ++nt)
          acc[mt][nt] = __builtin_amdgcn_mfma_f32_16x16x32_bf16(af[mt], bfr[nt], acc[mt][nt], 0,0,0);
      if (ch < 3){
        const int nxt = cur ^ 1;
#pragma unroll
        for (int half=0; half<2; ++half){
          int sl = t + half*256; int r = sl>>2, p = sl&3;
          *(bshort8*)&Bt[nxt][r*40+p*8] = bV[half];
        }
      }
    }
  }

  if constexpr (PHASE==2){
#pragma unroll
    for (int nt=0; nt<4; ++nt){
      float s=0.f, s2=0.f;
#pragma unroll
      for (int mt=0; mt<4; ++mt)
#pragma unroll
        for (int r=0; r<4; ++r){ float v=acc[mt][nt][r]; s+=v; s2=fmaf(v,v,s2); }
      s  += __shfl_xor(s,16,64);  s  += __shfl_xor(s,32,64);
      s2 += __shfl_xor(s2,16,64); s2 += __shfl_xor(s2,32,64);
      if (lane<16){
        int c = wn*64+nt*16+lane;
        atomicAdd(&slots[(slot*128+c)*2+0], s);
        atomicAdd(&slots[(slot*128+c)*2+1], s2);
      }
    }
    if constexpr (STOREY2){
      // raw y2 -> Y (bf16), then coalesced 16B stores
      __syncthreads();
#pragma unroll
      for (int nt=0; nt<4; ++nt){
        int c = wn*64+nt*16+lrow;
#pragma unroll
        for (int mt=0; mt<4; ++mt)
#pragma unroll
          for (int r=0; r<4; ++r){
            int row = wm*64+mt*16+quad*4+r;
            Y[row*136 + c] = f2bf(acc[mt][nt][r]);
          }
      }
      __syncthreads();
      for (int idx=t; idx<128*16; idx+=256){
        int r = idx>>4, p = idx&15;
        bshort8 v = *(const bshort8*)&Y[r*136 + p*8];
        *(bshort8*)(y2out + ((size_t)mblk*128 + r)*128 + p*8) = v;
      }
    }
    return;
  }

  if constexpr (PHASE==3){
    __syncthreads();
#pragma unroll
    for (int nt=0; nt<4; ++nt){
      int c = wn*64+nt*16+lrow;
      float sc = ss2[c], sh = ss2[128+c];
#pragma unroll
      for (int mt=0; mt<4; ++mt)
#pragma unroll
        for (int r=0; r<4; ++r){
          int row = wm*64+mt*16+quad*4+r;
          Y[row*136 + c] = f2bf(fmaxf(fmaf(acc[mt][nt][r], sc, sh), 0.f));
        }
    }

    for (int h=0; h<2; ++h){
#pragma unroll
      for (int i=0;i<4;++i)
#pragma unroll
        for (int j=0;j<4;++j) acc[i][j]=z4;
      bshort8 bV[2];
#pragma unroll
      for (int half=0; half<2; ++half){
        int sl = t + half*256; int r = sl>>2, p = sl&3;
        bV[half] = *(const bshort8*)(Wt3 + ((size_t)(h*128+r))*128 + p*8);
      }
#pragma unroll
      for (int half=0; half<2; ++half){
        int sl = t + half*256; int r = sl>>2, p = sl&3;
        *(bshort8*)&Bt[1][r*40+p*8] = bV[half];
      }
      for (int ch=0; ch<4; ++ch){
        const int cur = (ch & 1) ^ 1;
        __syncthreads();
        bshort8 af[4], bfr[4];
#pragma unroll
        for (int mt=0; mt<4; ++mt) af[mt]  = *(const bshort8*)&Y[(wm*64+mt*16+lrow)*136 + ch*32 + quad*8];
#pragma unroll
        for (int nt=0; nt<4; ++nt) bfr[nt] = *(const bshort8*)&Bt[cur][(wn*64+nt*16+lrow)*40 + quad*8];
        if (ch < 3){
#pragma unroll
          for (int half=0; half<2; ++half){
            int sl = t + half*256; int r = sl>>2, p = sl&3;
            bV[half] = *(const bshort8*)(Wt3 + ((size_t)(h*128+r))*128 + (ch+1)*32 + p*8);
          }
        }
#pragma unroll
        for (int mt=0; mt<4; ++mt)
#pragma unroll
          for (int nt=0; nt<4; ++nt)
            acc[mt][nt] = __builtin_amdgcn_mfma_f32_16x16x32_bf16(af[mt], bfr[nt], acc[mt][nt], 0,0,0);
        if (ch < 3){
          const int nxt = cur ^ 1;
#pragma unroll
          for (int half=0; half<2; ++half){
            int sl = t + half*256; int r = sl>>2, p = sl&3;
            *(bshort8*)&Bt[nxt][r*40+p*8] = bV[half];
          }
        }
      }
#pragma unroll
      for (int nt=0; nt<4; ++nt){
        float s=0.f, s2=0.f, mx=-3.0e38f, mn=3.0e38f;
#pragma unroll
        for (int mt=0; mt<4; ++mt)
#pragma unroll
          for (int r=0; r<4; ++r){
            float v=acc[mt][nt][r];
            s+=v; s2=fmaf(v,v,s2);
            mx=fmaxf(mx,v); mn=fminf(mn,v);
          }
        s  += __shfl_xor(s,16,64);  s  += __shfl_xor(s,32,64);
        s2 += __shfl_xor(s2,16,64); s2 += __shfl_xor(s2,32,64);
        mx = fmaxf(mx, __shfl_xor(mx,16,64)); mx = fmaxf(mx, __shfl_xor(mx,32,64));
        mn = fminf(mn, __shfl_xor(mn,16,64)); mn = fminf(mn, __shfl_xor(mn,32,64));
        if (lane<16){
          int c = h*128 + wn*64+nt*16+lane;
          atomicAdd(&slots[(slot*256+c)*2+0], s);
          atomicAdd(&slots[(slot*256+c)*2+1], s2);
          size_t sidx = (size_t)mblk*2 + wm;
          maxv[sidx*256 + c] = mx;
          minv[sidx*256 + c] = mn;
        }
      }
    }
  }
}

// ---------------------------------------------------------------------------
// mm3 (y2-load path): load raw y2 bf16, BN2+ReLU -> z2(Y), GEMM3 (2 halves).
// No gi/P/GEMM2 recompute.
// ---------------------------------------------------------------------------
__global__ __launch_bounds__(256,2) void mm3_kernel(
    const unsigned short* __restrict__ y2,
    const unsigned short* __restrict__ Wt3,
    const float* __restrict__ ss2,
    float* __restrict__ slots,
    float* __restrict__ minv,
    float* __restrict__ maxv)
{
  __shared__ alignas(16) unsigned short Bt[2][128*40];
  __shared__ alignas(16) unsigned short Y[128*136];
  const int t = threadIdx.x;
  const int mblk = blockIdx.x;
  const int lane = t&63, wave = t>>6;
  const int wm = wave>>1, wn = wave&1;
  const int lrow = lane&15, quad = lane>>4;
  const int slot = mblk & 63;

  // stage z2 = relu(y2*sc + sh) into Y
  {
    const int rgrp = t>>5, cq = (t&31)*4;
    f32x4 a2 = *(const f32x4*)(ss2 + cq);
    f32x4 b2 = *(const f32x4*)(ss2 + 128 + cq);
#pragma unroll
    for (int g=0; g<16; ++g){
      int r = g*8 + rgrp;
      us4 yv = *(const us4*)(y2 + ((size_t)mblk*128 + r)*128 + cq);
      us4 zz;
#pragma unroll
      for (int e=0;e<4;++e)
        zz[e] = f2bf(fmaxf(fmaf(bf2f(yv[e]), a2[e], b2[e]), 0.f));
      *(us4*)&Y[r*136 + cq] = zz;
    }
  }

  f32x4 acc[4][4];
  const f32x4 z4 = {0.f,0.f,0.f,0.f};
  for (int h=0; h<2; ++h){
#pragma unroll
    for (int i=0;i<4;++i)
#pragma unroll
      for (int j=0;j<4;++j) acc[i][j]=z4;
    bshort8 bV[2];
#pragma unroll
    for (int half=0; half<2; ++half){
      int sl = t + half*256; int r = sl>>2, p = sl&3;
      bV[half] = *(const bshort8*)(Wt3 + ((size_t)(h*128+r))*128 + p*8);
    }
#pragma unroll
    for (int half=0; half<2; ++half){
      int sl = t + half*256; int r = sl>>2, p = sl&3;
      *(bshort8*)&Bt[1][r*40+p*8] = bV[half];
    }
    for (int ch=0; ch<4; ++ch){
      const int cur = (ch & 1) ^ 1;
      __syncthreads();   // first iter also covers the Y staging
      bshort8 af[4], bfr[4];
#pragma unroll
      for (int mt=0; mt<4; ++mt) af[mt]  = *(const bshort8*)&Y[(wm*64+mt*16+lrow)*136 + ch*32 + quad*8];
#pragma unroll
      for (int nt=0; nt<4; ++nt) bfr[nt] = *(const bshort8*)&Bt[cur][(wn*64+nt*16+lrow)*40 + quad*8];
      if (ch < 3){
#pragma unroll
        for (int half=0; half<2; ++half){
          int sl = t + half*256; int r = sl>>2, p = sl&3;
          bV[half] = *(const bshort8*)(Wt3 + ((size_t)(h*128+r))*128 + (ch+1)*32 + p*8);
        }
      }
#pragma unroll
      for (int mt=0; mt<4; ++mt)
#pragma unroll
        for (int nt=0; nt<4; ++nt)
          acc[mt][nt] = __builtin_amdgcn_mfma_f32_16x16x32_bf16(af[mt], bfr[nt], acc[mt][nt], 0,0,0);
      if (ch < 3){
        const int nxt = cur ^ 1;
#pragma unroll
        for (int half=0; half<2; ++half){
          int sl = t + half*256; int r = sl>>2, p = sl&3;
          *(bshort8*)&Bt[nxt][r*40+p*8] = bV[half];
        }
      }
    }
#pragma unroll
    for (int nt=0; nt<4; ++nt){
      float s=0.f, s2=0.f, mx=-3.0e38f, mn=3.0e38f;
#pragma unroll
      for (int mt=0; mt<4; ++mt)
#pragma unroll
        for (int r=0; r<4; ++r){
          float v=acc[mt][nt][r];
          s+=v; s2=fmaf(v,v,s2);
          mx=fmaxf(mx,v); mn=fminf(mn,v);
        }
      s  += __shfl_xor(s,16,64);  s  += __shfl_xor(s,32,64);
      s2 += __shfl_xor(s2,16,64); s2 += __shfl_xor(s2,32,64);
      mx = fmaxf(mx, __shfl_xor(mx,16,64)); mx = fmaxf(mx, __shfl_xor(mx,32,64));
      mn = fminf(mn, __shfl_xor(mn,16,64)); mn = fminf(mn, __shfl_xor(mn,32,64));
      if (lane<16){
        int c = h*128 + wn*64+nt*16+lane;
        atomicAdd(&slots[(slot*256+c)*2+0], s);
        atomicAdd(&slots[(slot*256+c)*2+1], s2);
        size_t sidx = (size_t)mblk*2 + wm;
        maxv[sidx*256 + c] = mx;
        minv[sidx*256 + c] = mn;
      }
    }
    if (h==0) __syncthreads();   // protect Y reads vs nothing (Y unchanged) — keeps parity
  }
}

// ---------------------------------------------------------------------------
__global__ void stats_kernel(const float* __restrict__ slots, const float* __restrict__ g,
                             const float* __restrict__ beta, float* __restrict__ ssOut,
                             int C, float inv_cnt){
  int c = threadIdx.x;
  if (c >= C) return;
  float s=0.f, s2=0.f;
  for (int k=0;k<64;++k){
    s  += slots[(k*C + c)*2 + 0];
    s2 += slots[(k*C + c)*2 + 1];
  }
  float m = s * inv_cnt;
  float v = fmaxf(s2 * inv_cnt - m*m, 0.f);
  float sc = rsqrtf(v + 1e-5f) * g[c];
  ssOut[c] = sc;
  ssOut[C + c] = beta[c] - m*sc;
}

// ---------------------------------------------------------------------------
__global__ __launch_bounds__(256) void final_kernel(const float* __restrict__ minv,
                                                    const float* __restrict__ maxv,
                                                    const float* __restrict__ ss3,
                                                    float* __restrict__ out){
  __shared__ float tile[64][65];
  const int t = threadIdx.x;
  const int cb = blockIdx.x;
  const int sb = blockIdx.y;
  const int b  = blockIdx.z;
  const int w = t>>6, l = t&63;
  {
    int c = cb*64 + l;
    float sc = ss3[c], sh = ss3[256+c];
#pragma unroll
    for (int k=0;k<16;++k){
      int sl = k*4 + w;
      size_t mi = ((size_t)(b*1024 + sb*64 + sl))*256 + c;
      float v = (sc >= 0.f) ? maxv[mi] : minv[mi];
      tile[sl][l] = fmaxf(fmaf(v, sc, sh), 0.f);
    }
  }
  __syncthreads();
#pragma unroll
  for (int k=0;k<16;++k){
    int cl = k*4 + w;
    out[((size_t)(b*256 + cb*64 + cl))*1024 + sb*64 + l] = tile[l][cl];
  }
}

// ---------------------------------------------------------------------------
extern "C" void kernel_launch(void* const* d_in, const int* in_sizes, int n_in,
                              void* d_out, int out_size, void* d_ws, size_t ws_size,
                              hipStream_t stream){
  const float* xyz      = (const float*)d_in[0];
  const float* features = (const float*)d_in[1];
  const float* W1 = (const float*)d_in[2];
  const float* g1 = (const float*)d_in[3];
  const float* b1 = (const float*)d_in[4];
  const float* W2 = (const float*)d_in[5];
  const float* g2 = (const float*)d_in[6];
  const float* b2 = (const float*)d_in[7];
  const float* W3 = (const float*)d_in[8];
  const float* g3 = (const float*)d_in[9];
  const float* b3 = (const float*)d_in[10];
  float* out = (float*)d_out;

  char* ws = (char*)d_ws;
  size_t off = 0;
  auto alloc = [&](size_t bytes)->char*{
    char* p = ws + off;
    off = (off + bytes + 255) & ~(size_t)255;
    return p;
  };
  float* slots1 = (float*)alloc((size_t)64*128*2*4);
  float* slots2 = (float*)alloc((size_t)64*128*2*4);
  float* slots3 = (float*)alloc((size_t)64*256*2*4);
  float* ss1    = (float*)alloc(256*4);
  float* ss2    = (float*)alloc(256*4);
  float* ss3    = (float*)alloc(512*4);
  float* nxyz   = (float*)alloc((size_t)24576*4);
  int*   gi     = (int*)  alloc((size_t)M_*4);
  unsigned short* featT = (unsigned short*)alloc((size_t)B_*N_*CF_*2);
  unsigned short* Wt1   = (unsigned short*)alloc((size_t)128*160*2);
  unsigned short* Wt2   = (unsigned short*)alloc((size_t)128*128*2);
  unsigned short* Wt3   = (unsigned short*)alloc((size_t)256*128*2);
  float* minv = (float*)alloc((size_t)B_*S_*256*4);
  float* maxv = (float*)alloc((size_t)B_*S_*256*4);
  float* P    = (float*)alloc((size_t)B_*N_*128*4);   // 16.8 MB
  size_t base_end = off;
  unsigned short* y2 = (unsigned short*)alloc((size_t)M_*128*2);  // 134 MB
  const bool bigws = (off <= ws_size);   // constant across calls -> capture-safe
  (void)base_end;

  hipMemsetAsync(slots1, 0, (size_t)(64*128*2 + 64*128*2 + 64*256*2)*4, stream);

  prep_kernel<<<4160, 256, 0, stream>>>(features, W1, W2, W3, featT, Wt1, Wt2, Wt3);
  pgemm_kernel<<<256, 256, 0, stream>>>(featT, Wt1, P);
  fps_kernel<<<8, 512, 0, stream>>>(xyz, out, nxyz);
  qbp_y1_kernel<<<2048, 256, 0, stream>>>(xyz, nxyz, P, W1, gi, slots1);

  const float inv_cnt = 1.0f / (float)M_;
  stats_kernel<<<1, 128, 0, stream>>>(slots1, g1, b1, ss1, 128, inv_cnt);
  if (bigws){
    mm_fused<2,true><<<4096, 256, 0, stream>>>(P, W1, Wt2, Wt3, gi, xyz, nxyz,
                                               ss1, nullptr, slots2, nullptr, nullptr, y2);
    stats_kernel<<<1, 128, 0, stream>>>(slots2, g2, b2, ss2, 128, inv_cnt);
    mm3_kernel<<<4096, 256, 0, stream>>>(y2, Wt3, ss2, slots3, minv, maxv);
  } else {
    mm_fused<2,false><<<4096, 256, 0, stream>>>(P, W1, Wt2, Wt3, gi, xyz, nxyz,
                                                ss1, nullptr, slots2, nullptr, nullptr, nullptr);
    stats_kernel<<<1, 128, 0, stream>>>(slots2, g2, b2, ss2, 128, inv_cnt);
    mm_fused<3,false><<<4096, 256, 0, stream>>>(P, W1, Wt2, Wt3, gi, xyz, nxyz,
                                                ss1, ss2, slots3, minv, maxv, nullptr);
  }
  stats_kernel<<<1, 256, 0, stream>>>(slots3, g3, b3, ss3, 256, inv_cnt);
  final_kernel<<<dim3(4,16,8), 256, 0, stream>>>(minv, maxv, ss3, out + 24576);
}

// Round 13
// 1084.723 us; speedup vs baseline: 1.1977x; 1.1977x over previous
//
#include <hip/hip_runtime.h>

#define B_  8
#define N_  4096
#define S_  1024
#define K_  64
#define CF_ 128
#define M_  (B_*S_*K_)   // 524288 rows per layer

typedef __attribute__((ext_vector_type(8))) short bshort8;
typedef __attribute__((ext_vector_type(4))) float f32x4;
typedef __attribute__((ext_vector_type(4))) int   i32x4;
typedef __attribute__((ext_vector_type(2))) float f32x2;
typedef __attribute__((ext_vector_type(4))) unsigned short us4;

__device__ __forceinline__ unsigned short f2bf(float f){
  unsigned int u = __float_as_uint(f);
  u = u + 0x7FFFu + ((u >> 16) & 1u);      // RTNE
  return (unsigned short)(u >> 16);
}
__device__ __forceinline__ float bf2f(unsigned short h){
  return __uint_as_float(((unsigned int)h) << 16);
}

// ---------------------------------------------------------------------------
// prep: transpose (blocks 0..4095) + weight prep (blocks 4096..4159)
// ---------------------------------------------------------------------------
__global__ __launch_bounds__(256) void prep_kernel(const float* __restrict__ f,
                                                   const float* __restrict__ W1,
                                                   const float* __restrict__ W2,
                                                   const float* __restrict__ W3,
                                                   unsigned short* __restrict__ ft,
                                                   unsigned short* __restrict__ Wt1,
                                                   unsigned short* __restrict__ Wt2,
                                                   unsigned short* __restrict__ Wt3){
  __shared__ float tile[32][33];
  const int blk = blockIdx.x;
  if (blk < 4096){
    int nt = blk & 127, ct = (blk>>7)&3, b = blk>>9;
    int tx = threadIdx.x & 31, ty = threadIdx.x >> 5;
#pragma unroll
    for (int r=0; r<32; r+=8)
      tile[ty+r][tx] = f[((size_t)(b*128 + ct*32 + ty + r))*4096 + nt*32 + tx];
    __syncthreads();
#pragma unroll
    for (int r=0; r<32; r+=8){
      int n = nt*32 + ty + r, cc = ct*32 + tx;
      ft[((size_t)b*4096 + n)*128 + cc] = f2bf(tile[tx][ty+r]);
    }
  } else {
    int t = (blk-4096)*256 + threadIdx.x;
    int stride = 64*256;
    for (int idx=t; idx<128*160; idx+=stride){
      int n = idx/160, k = idx-(idx/160)*160;
      float v = 0.f;
      if (k < 128) v = W1[(k+3)*128 + n];
      else if (k < 131) v = W1[(k-128)*128 + n];
      Wt1[idx] = f2bf(v);
    }
    for (int idx=t; idx<128*128; idx+=stride){
      int n = idx>>7, k = idx&127;
      Wt2[idx] = f2bf(W2[k*128+n]);
    }
    for (int idx=t; idx<256*128; idx+=stride){
      int n = idx>>7, k = idx&127;
      Wt3[idx] = f2bf(W3[k*256+n]);
    }
  }
}

// ---------------------------------------------------------------------------
// pgemm: P = featT x W1_feat (f32 out), standalone (r10 version).
// ---------------------------------------------------------------------------
__global__ __launch_bounds__(256,2) void pgemm_kernel(const unsigned short* __restrict__ featT,
                                                      const unsigned short* __restrict__ Wt1,
                                                      float* __restrict__ P){
  __shared__ alignas(16) unsigned short At[128*40];
  __shared__ alignas(16) unsigned short Bt[128*40];
  const int t = threadIdx.x, blk = blockIdx.x;     // 256 blocks
  const size_t rowBase = (size_t)blk*128;
  const int lane = t&63, wave = t>>6;
  const int wm = wave>>1, wn = wave&1;
  const int lrow = lane&15, quad = lane>>4;
  f32x4 acc[4][4];
  const f32x4 z4 = {0.f,0.f,0.f,0.f};
#pragma unroll
  for (int i=0;i<4;++i)
#pragma unroll
    for (int j=0;j<4;++j) acc[i][j]=z4;
  for (int ch=0; ch<4; ++ch){
    __syncthreads();
#pragma unroll
    for (int half=0; half<2; ++half){
      int sl = t + half*256; int r = sl>>2, p = sl&3;
      *(bshort8*)&At[r*40+p*8] = *(const bshort8*)(featT + (rowBase + r)*CF_ + ch*32 + p*8);
      *(bshort8*)&Bt[r*40+p*8] = *(const bshort8*)(Wt1 + r*160 + ch*32 + p*8);
    }
    __syncthreads();
    bshort8 af[4], bfr[4];
#pragma unroll
    for (int mt=0; mt<4; ++mt) af[mt]  = *(const bshort8*)&At[(wm*64+mt*16+lrow)*40 + quad*8];
#pragma unroll
    for (int nt=0; nt<4; ++nt) bfr[nt] = *(const bshort8*)&Bt[(wn*64+nt*16+lrow)*40 + quad*8];
#pragma unroll
    for (int mt=0; mt<4; ++mt)
#pragma unroll
      for (int nt=0; nt<4; ++nt)
        acc[mt][nt] = __builtin_amdgcn_mfma_f32_16x16x32_bf16(af[mt], bfr[nt], acc[mt][nt], 0,0,0);
  }
#pragma unroll
  for (int mt=0; mt<4; ++mt)
#pragma unroll
    for (int nt=0; nt<4; ++nt)
#pragma unroll
      for (int r=0; r<4; ++r){
        int row = wm*64 + mt*16 + quad*4 + r;
        int col = wn*64 + nt*16 + lrow;
        P[(rowBase + row)*128 + col] = acc[mt][nt][r];
      }
}

// ---------------------------------------------------------------------------
// FPS: r7 EXACT (measured 793us floor). Ledger: serial=793, prefetch=843,
// tree=947, 512t=982. Latency-bound serial chain; barrier-locked waves mean
// more waves DON'T hide it (r8 counter-verified). DO NOT TOUCH.
// ---------------------------------------------------------------------------
#define DPP_PAIR_STEP(CTRL)                                                     \
  {                                                                             \
    int _vi = __builtin_amdgcn_update_dpp(__float_as_int(best), __float_as_int(best), (CTRL), 0xF, 0xF, false); \
    int _ii = __builtin_amdgcn_update_dpp(bidx, bidx, (CTRL), 0xF, 0xF, false); \
    float _ov = __int_as_float(_vi);                                            \
    bool _tk = (_ov > best) || (_ov == best && _ii < bidx);                     \
    best = _tk ? _ov : best;                                                    \
    bidx = _tk ? _ii : bidx;                                                    \
  }

__global__ __launch_bounds__(256) void fps_kernel(const float* __restrict__ xyz,
                                                  float* __restrict__ nx_out,
                                                  float* __restrict__ nx_ws){
#pragma clang fp contract(off)
  __shared__ float sx[N_], sy[N_], sz[N_];
  __shared__ int   sidx[S_];
  __shared__ alignas(16) float redv[2][4];
  __shared__ alignas(16) int   redi[2][4];
  const int b = blockIdx.x, t = threadIdx.x;
  const int lane = t & 63, w = t >> 6;
  const float* xb = xyz + (size_t)b*N_*3;
  f32x2 px[8], py[8], pz[8], dist[8];
#pragma unroll
  for (int j=0;j<8;++j){
    int i0 = (2*j)*256 + t, i1 = (2*j+1)*256 + t;
    float x0=xb[i0*3+0], y0=xb[i0*3+1], z0=xb[i0*3+2];
    float x1=xb[i1*3+0], y1=xb[i1*3+1], z1=xb[i1*3+2];
    px[j] = (f32x2){x0,x1}; py[j] = (f32x2){y0,y1}; pz[j] = (f32x2){z0,z1};
    dist[j] = (f32x2){1e10f,1e10f};
    sx[i0]=x0; sy[i0]=y0; sz[i0]=z0;
    sx[i1]=x1; sy[i1]=y1; sz[i1]=z1;
  }
  __syncthreads();
  int farthest = 0;
  for (int it=0; it<S_; ++it){
    if (t==0) sidx[it] = farthest;
    float cx = sx[farthest], cy = sy[farthest], cz = sz[farthest];
    f32x2 cx2 = (f32x2){cx,cx}, cy2 = (f32x2){cy,cy}, cz2 = (f32x2){cz,cz};
    float best = -1.0f; int bidx = 0;
#pragma unroll
    for (int j=0;j<8;++j){
      f32x2 dx = px[j] - cx2;
      f32x2 dy = py[j] - cy2;
      f32x2 dz = pz[j] - cz2;
      f32x2 d  = (dx*dx + dy*dy) + dz*dz;
      f32x2 nd;
      nd.x = fminf(dist[j].x, d.x);
      nd.y = fminf(dist[j].y, d.y);
      dist[j] = nd;
      bool tk0 = nd.x > best;
      best = tk0 ? nd.x : best;
      bidx = tk0 ? ((2*j)*256 + t) : bidx;
      bool tk1 = nd.y > best;
      best = tk1 ? nd.y : best;
      bidx = tk1 ? ((2*j+1)*256 + t) : bidx;
    }
    DPP_PAIR_STEP(0xB1);
    DPP_PAIR_STEP(0x4E);
    DPP_PAIR_STEP(0x124);
    DPP_PAIR_STEP(0x128);
    DPP_PAIR_STEP(0x142);
    DPP_PAIR_STEP(0x143);
    const int buf = it & 1;
    if (lane == 63){ redv[buf][w] = best; redi[buf][w] = bidx; }
    __syncthreads();
    f32x4 vv = *(const f32x4*)&redv[buf][0];
    i32x4 iv = *(const i32x4*)&redi[buf][0];
    float v01 = vv[0]; int i01 = iv[0];
    { bool tk = (vv[1] > v01) || (vv[1] == v01 && iv[1] < i01); v01 = tk?vv[1]:v01; i01 = tk?iv[1]:i01; }
    float v23 = vv[2]; int i23 = iv[2];
    { bool tk = (vv[3] > v23) || (vv[3] == v23 && iv[3] < i23); v23 = tk?vv[3]:v23; i23 = tk?iv[3]:i23; }
    { bool tk = (v23 > v01) || (v23 == v01 && i23 < i01); v01 = tk?v23:v01; i01 = tk?i23:i01; }
    farthest = i01;
  }
  __syncthreads();
  for (int i=t; i<S_; i+=256){
    int id = sidx[i];
    size_t base = (size_t)(b*S_+i)*3;
    float vx=sx[id], vy=sy[id], vz=sz[id];
    nx_out[base+0]=vx; nx_out[base+1]=vy; nx_out[base+2]=vz;
    nx_ws[base+0]=vx;  nx_ws[base+1]=vy;  nx_ws[base+2]=vz;
  }
}

// ---------------------------------------------------------------------------
// qbp + y1 column stats fused (r11-exact).
// ---------------------------------------------------------------------------
__global__ __launch_bounds__(256) void qbp_y1_kernel(const float* __restrict__ xyz,
                                                     const float* __restrict__ nx,
                                                     const float* __restrict__ P,
                                                     const float* __restrict__ W1,
                                                     int* __restrict__ gi,
                                                     float* __restrict__ slots){
  __shared__ int giW[4][64];
  __shared__ alignas(16) float dxL[4][64][4];
  __shared__ float sLDS[128], s2LDS[128];
  const int t = threadIdx.x;
  const int lane = t & 63, w = t >> 6;
  if (t < 128){ sLDS[t]=0.f; s2LDS[t]=0.f; }
  __syncthreads();
  const int wid = blockIdx.x*4 + w;
  const int b = wid >> 10, s = wid & 1023;
  const float* xb = xyz + (size_t)b*N_*3;
  {
    const double R2 = 0.2*0.2;
    const float* c  = nx + (size_t)(b*S_+s)*3;
    double cx=(double)c[0], cy=(double)c[1], cz=(double)c[2];
    double cc = cx*cx + cy*cy + cz*cz;
    int* g = gi + (size_t)(b*S_+s)*K_;
    int count = 0, first = -1;
    for (int ch=0; ch<64 && count<K_; ++ch){
      int i = ch*64 + lane;
      double x = (double)xb[i*3+0], y = (double)xb[i*3+1], z = (double)xb[i*3+2];
      double e  = cx*x + cy*y + cz*z;
      double pp = x*x + y*y + z*z;
      double d  = -2.0*e + cc + pp;
      bool keep = !(d > R2);
      unsigned long long bal = __ballot(keep);
      int pos = count + __builtin_popcountll(bal & ((1ull<<lane)-1ull));
      if (keep && pos < K_){ g[pos] = i; giW[w][pos] = i; }
      if (first < 0 && bal) first = ch*64 + (int)__builtin_ctzll(bal);
      count += __builtin_popcountll(bal);
    }
    if (count < K_){
      int p = count + lane;
      if (p < K_){ g[p] = first; giW[w][p] = first; }
    }
    int i = giW[w][lane];
    const float* pp = xyz + ((size_t)b*N_ + i)*3;
    const float* qq = nx  + (size_t)(b*S_ + s)*3;
    dxL[w][lane][0] = __fsub_rn(pp[0],qq[0]);
    dxL[w][lane][1] = __fsub_rn(pp[1],qq[1]);
    dxL[w][lane][2] = __fsub_rn(pp[2],qq[2]);
  }
  {
    const int cq = lane*2;
    f32x2 w0 = *(const f32x2*)(W1 + cq);
    f32x2 w1v = *(const f32x2*)(W1 + 128 + cq);
    f32x2 w2 = *(const f32x2*)(W1 + 256 + cq);
    f32x2 sA = {0,0}, s2A = {0,0};
#pragma unroll 4
    for (int r=0; r<64; ++r){
      int pi = giW[w][r];
      f32x2 p = *(const f32x2*)(P + ((size_t)b*N_ + pi)*128 + cq);
      float dx = dxL[w][r][0], dy = dxL[w][r][1], dz = dxL[w][r][2];
      f32x2 y;
#pragma unroll
      for (int e=0;e<2;++e)
        y[e] = fmaf(dz, w2[e], fmaf(dy, w1v[e], fmaf(dx, w0[e], p[e])));
      sA.x += y.x; sA.y += y.y;
      s2A.x = fmaf(y.x,y.x,s2A.x); s2A.y = fmaf(y.y,y.y,s2A.y);
    }
    atomicAdd(&sLDS[cq],    sA.x);  atomicAdd(&sLDS[cq+1],  sA.y);
    atomicAdd(&s2LDS[cq],   s2A.x); atomicAdd(&s2LDS[cq+1], s2A.y);
  }
  __syncthreads();
  if (t < 128){
    int slot = blockIdx.x & 63;
    atomicAdd(&slots[(slot*128+t)*2+0], sLDS[t]);
    atomicAdd(&slots[(slot*128+t)*2+1], s2LDS[t]);
  }
}

// ---------------------------------------------------------------------------
// mm_fused: single-buffered Bt (weights are L2-resident; dbuf only hid an
// L2-hit load) cuts LDS 55.3->48 KB => 3 blocks/CU (was 2). m97-ladder
// precedent: 3->2 blocks/CU on this kernel shape cost 42%. Numerics
// bit-identical (same data, same MFMA order; +1 barrier/chunk).
// ---------------------------------------------------------------------------
template<int PHASE, bool STOREY2>
__global__ __launch_bounds__(256,3) void mm_fused(
    const float* __restrict__ P,
    const float* __restrict__ W1,
    const unsigned short* __restrict__ Wt2,
    const unsigned short* __restrict__ Wt3,
    const int* __restrict__ gi,
    const float* __restrict__ xyz,
    const float* __restrict__ nxyz,
    const float* __restrict__ ss1,
    const float* __restrict__ ss2,
    float* __restrict__ slots,
    float* __restrict__ minv,
    float* __restrict__ maxv,
    unsigned short* __restrict__ y2out)
{
  __shared__ alignas(16) unsigned short Bt[128*40];
  __shared__ alignas(16) unsigned short Y[128*136];
  __shared__ int giL[128];
  __shared__ alignas(16) float dxL[128][4];
  __shared__ alignas(16) float w0L[128], w1L[128], w2L[128];

  const int t = threadIdx.x;
  const int mblk = blockIdx.x;
  const int b = mblk >> 9;
  const int lane = t&63, wave = t>>6;
  const int wm = wave>>1, wn = wave&1;
  const int lrow = lane&15, quad = lane>>4;
  const int slot = mblk & 63;

  if (t<128){
    int i = gi[(size_t)mblk*128 + t];
    giL[t] = i;
    int s = ((mblk*128 + t) >> 6) & 1023;
    const float* pp = xyz  + ((size_t)b*N_ + i)*3;
    const float* qq = nxyz + (size_t)(b*S_ + s)*3;
    dxL[t][0] = __fsub_rn(pp[0],qq[0]);
    dxL[t][1] = __fsub_rn(pp[1],qq[1]);
    dxL[t][2] = __fsub_rn(pp[2],qq[2]);
    w0L[t] = W1[t]; w1L[t] = W1[128+t]; w2L[t] = W1[256+t];
  }
  __syncthreads();

  // ---- y1 + BN1 + ReLU -> Y ----
  {
    const int rgrp = t>>5, cq = (t&31)*4;
    f32x4 w0 = *(const f32x4*)&w0L[cq];
    f32x4 w1 = *(const f32x4*)&w1L[cq];
    f32x4 w2 = *(const f32x4*)&w2L[cq];
    f32x4 a1v = *(const f32x4*)(ss1 + cq);
    f32x4 b1v = *(const f32x4*)(ss1 + 128 + cq);
#pragma unroll
    for (int g=0; g<16; ++g){
      int r = g*8 + rgrp;
      int pi = giL[r];
      f32x4 p = *(const f32x4*)(P + ((size_t)b*N_ + pi)*128 + cq);
      float dx = dxL[r][0], dy = dxL[r][1], dz = dxL[r][2];
      f32x4 y;
#pragma unroll
      for (int e=0;e<4;++e)
        y[e] = fmaf(dz, w2[e], fmaf(dy, w1[e], fmaf(dx, w0[e], p[e])));
      us4 zz;
#pragma unroll
      for (int e=0;e<4;++e)
        zz[e] = f2bf(fmaxf(fmaf(y[e], a1v[e], b1v[e]), 0.f));
      *(us4*)&Y[r*136 + cq] = zz;
    }
  }

  f32x4 acc[4][4];
  const f32x4 z4 = {0.f,0.f,0.f,0.f};
#pragma unroll
  for (int i=0;i<4;++i)
#pragma unroll
    for (int j=0;j<4;++j) acc[i][j]=z4;

  // ---------------- GEMM2 (single-buf): A = Y (z1), K=128 ----------------
  for (int ch=0; ch<4; ++ch){
    bshort8 bV[2];
#pragma unroll
    for (int half=0; half<2; ++half){
      int sl = t + half*256; int r = sl>>2, p = sl&3;
      bV[half] = *(const bshort8*)(Wt2 + r*128 + ch*32 + p*8);
    }
    __syncthreads();   // prior iter's Bt reads done (iter0: Y writes ordered)
#pragma unroll
    for (int half=0; half<2; ++half){
      int sl = t + half*256; int r = sl>>2, p = sl&3;
      *(bshort8*)&Bt[r*40+p*8] = bV[half];
    }
    __syncthreads();
    bshort8 af[4], bfr[4];
#pragma unroll
    for (int mt=0; mt<4; ++mt) af[mt]  = *(const bshort8*)&Y[(wm*64+mt*16+lrow)*136 + ch*32 + quad*8];
#pragma unroll
    for (int nt=0; nt<4; ++nt) bfr[nt] = *(const bshort8*)&Bt[(wn*64+nt*16+lrow)*40 + quad*8];
#pragma unroll
    for (int mt=0; mt<4; ++mt)
#pragma unroll
      for (int nt=0; nt<4; ++nt)
        acc[mt][nt] = __builtin_amdgcn_mfma_f32_16x16x32_bf16(af[mt], bfr[nt], acc[mt][nt], 0,0,0);
  }

  if constexpr (PHASE==2){
#pragma unroll
    for (int nt=0; nt<4; ++nt){
      float s=0.f, s2=0.f;
#pragma unroll
      for (int mt=0; mt<4; ++mt)
#pragma unroll
        for (int r=0; r<4; ++r){ float v=acc[mt][nt][r]; s+=v; s2=fmaf(v,v,s2); }
      s  += __shfl_xor(s,16,64);  s  += __shfl_xor(s,32,64);
      s2 += __shfl_xor(s2,16,64); s2 += __shfl_xor(s2,32,64);
      if (lane<16){
        int c = wn*64+nt*16+lane;
        atomicAdd(&slots[(slot*128+c)*2+0], s);
        atomicAdd(&slots[(slot*128+c)*2+1], s2);
      }
    }
    if constexpr (STOREY2){
      // raw y2 -> Y (bf16), then coalesced 16B stores
      __syncthreads();
#pragma unroll
      for (int nt=0; nt<4; ++nt){
        int c = wn*64+nt*16+lrow;
#pragma unroll
        for (int mt=0; mt<4; ++mt)
#pragma unroll
          for (int r=0; r<4; ++r){
            int row = wm*64+mt*16+quad*4+r;
            Y[row*136 + c] = f2bf(acc[mt][nt][r]);
          }
      }
      __syncthreads();
      for (int idx=t; idx<128*16; idx+=256){
        int r = idx>>4, p = idx&15;
        bshort8 v = *(const bshort8*)&Y[r*136 + p*8];
        *(bshort8*)(y2out + ((size_t)mblk*128 + r)*128 + p*8) = v;
      }
    }
    return;
  }

  if constexpr (PHASE==3){
    __syncthreads();
#pragma unroll
    for (int nt=0; nt<4; ++nt){
      int c = wn*64+nt*16+lrow;
      float sc = ss2[c], sh = ss2[128+c];
#pragma unroll
      for (int mt=0; mt<4; ++mt)
#pragma unroll
        for (int r=0; r<4; ++r){
          int row = wm*64+mt*16+quad*4+r;
          Y[row*136 + c] = f2bf(fmaxf(fmaf(acc[mt][nt][r], sc, sh), 0.f));
        }
    }

    for (int h=0; h<2; ++h){
#pragma unroll
      for (int i=0;i<4;++i)
#pragma unroll
        for (int j=0;j<4;++j) acc[i][j]=z4;
      for (int ch=0; ch<4; ++ch){
        bshort8 bV[2];
#pragma unroll
        for (int half=0; half<2; ++half){
          int sl = t + half*256; int r = sl>>2, p = sl&3;
          bV[half] = *(const bshort8*)(Wt3 + ((size_t)(h*128+r))*128 + ch*32 + p*8);
        }
        __syncthreads();   // prior iter's Bt reads done (h0ch0: z2 writes ordered)
#pragma unroll
        for (int half=0; half<2; ++half){
          int sl = t + half*256; int r = sl>>2, p = sl&3;
          *(bshort8*)&Bt[r*40+p*8] = bV[half];
        }
        __syncthreads();
        bshort8 af[4], bfr[4];
#pragma unroll
        for (int mt=0; mt<4; ++mt) af[mt]  = *(const bshort8*)&Y[(wm*64+mt*16+lrow)*136 + ch*32 + quad*8];
#pragma unroll
        for (int nt=0; nt<4; ++nt) bfr[nt] = *(const bshort8*)&Bt[(wn*64+nt*16+lrow)*40 + quad*8];
#pragma unroll
        for (int mt=0; mt<4; ++mt)
#pragma unroll
          for (int nt=0; nt<4; ++nt)
            acc[mt][nt] = __builtin_amdgcn_mfma_f32_16x16x32_bf16(af[mt], bfr[nt], acc[mt][nt], 0,0,0);
      }
#pragma unroll
      for (int nt=0; nt<4; ++nt){
        float s=0.f, s2=0.f, mx=-3.0e38f, mn=3.0e38f;
#pragma unroll
        for (int mt=0; mt<4; ++mt)
#pragma unroll
          for (int r=0; r<4; ++r){
            float v=acc[mt][nt][r];
            s+=v; s2=fmaf(v,v,s2);
            mx=fmaxf(mx,v); mn=fminf(mn,v);
          }
        s  += __shfl_xor(s,16,64);  s  += __shfl_xor(s,32,64);
        s2 += __shfl_xor(s2,16,64); s2 += __shfl_xor(s2,32,64);
        mx = fmaxf(mx, __shfl_xor(mx,16,64)); mx = fmaxf(mx, __shfl_xor(mx,32,64));
        mn = fminf(mn, __shfl_xor(mn,16,64)); mn = fminf(mn, __shfl_xor(mn,32,64));
        if (lane<16){
          int c = h*128 + wn*64+nt*16+lane;
          atomicAdd(&slots[(slot*256+c)*2+0], s);
          atomicAdd(&slots[(slot*256+c)*2+1], s2);
          size_t sidx = (size_t)mblk*2 + wm;
          maxv[sidx*256 + c] = mx;
          minv[sidx*256 + c] = mn;
        }
      }
    }
  }
}

// ---------------------------------------------------------------------------
// mm3 (y2-load path): single-buffered Bt => LDS 55.3->44 KB => 3 blocks/CU.
// ---------------------------------------------------------------------------
__global__ __launch_bounds__(256,3) void mm3_kernel(
    const unsigned short* __restrict__ y2,
    const unsigned short* __restrict__ Wt3,
    const float* __restrict__ ss2,
    float* __restrict__ slots,
    float* __restrict__ minv,
    float* __restrict__ maxv)
{
  __shared__ alignas(16) unsigned short Bt[128*40];
  __shared__ alignas(16) unsigned short Y[128*136];
  const int t = threadIdx.x;
  const int mblk = blockIdx.x;
  const int lane = t&63, wave = t>>6;
  const int wm = wave>>1, wn = wave&1;
  const int lrow = lane&15, quad = lane>>4;
  const int slot = mblk & 63;

  // stage z2 = relu(y2*sc + sh) into Y
  {
    const int rgrp = t>>5, cq = (t&31)*4;
    f32x4 a2 = *(const f32x4*)(ss2 + cq);
    f32x4 b2 = *(const f32x4*)(ss2 + 128 + cq);
#pragma unroll
    for (int g=0; g<16; ++g){
      int r = g*8 + rgrp;
      us4 yv = *(const us4*)(y2 + ((size_t)mblk*128 + r)*128 + cq);
      us4 zz;
#pragma unroll
      for (int e=0;e<4;++e)
        zz[e] = f2bf(fmaxf(fmaf(bf2f(yv[e]), a2[e], b2[e]), 0.f));
      *(us4*)&Y[r*136 + cq] = zz;
    }
  }

  f32x4 acc[4][4];
  const f32x4 z4 = {0.f,0.f,0.f,0.f};
  for (int h=0; h<2; ++h){
#pragma unroll
    for (int i=0;i<4;++i)
#pragma unroll
      for (int j=0;j<4;++j) acc[i][j]=z4;
    for (int ch=0; ch<4; ++ch){
      bshort8 bV[2];
#pragma unroll
      for (int half=0; half<2; ++half){
        int sl = t + half*256; int r = sl>>2, p = sl&3;
        bV[half] = *(const bshort8*)(Wt3 + ((size_t)(h*128+r))*128 + ch*32 + p*8);
      }
      __syncthreads();   // prior iter's Bt reads done (h0ch0: Y staging ordered)
#pragma unroll
      for (int half=0; half<2; ++half){
        int sl = t + half*256; int r = sl>>2, p = sl&3;
        *(bshort8*)&Bt[r*40+p*8] = bV[half];
      }
      __syncthreads();
      bshort8 af[4], bfr[4];
#pragma unroll
      for (int mt=0; mt<4; ++mt) af[mt]  = *(const bshort8*)&Y[(wm*64+mt*16+lrow)*136 + ch*32 + quad*8];
#pragma unroll
      for (int nt=0; nt<4; ++nt) bfr[nt] = *(const bshort8*)&Bt[(wn*64+nt*16+lrow)*40 + quad*8];
#pragma unroll
      for (int mt=0; mt<4; ++mt)
#pragma unroll
        for (int nt=0; nt<4; ++nt)
          acc[mt][nt] = __builtin_amdgcn_mfma_f32_16x16x32_bf16(af[mt], bfr[nt], acc[mt][nt], 0,0,0);
    }
#pragma unroll
    for (int nt=0; nt<4; ++nt){
      float s=0.f, s2=0.f, mx=-3.0e38f, mn=3.0e38f;
#pragma unroll
      for (int mt=0; mt<4; ++mt)
#pragma unroll
        for (int r=0; r<4; ++r){
          float v=acc[mt][nt][r];
          s+=v; s2=fmaf(v,v,s2);
          mx=fmaxf(mx,v); mn=fminf(mn,v);
        }
      s  += __shfl_xor(s,16,64);  s  += __shfl_xor(s,32,64);
      s2 += __shfl_xor(s2,16,64); s2 += __shfl_xor(s2,32,64);
      mx = fmaxf(mx, __shfl_xor(mx,16,64)); mx = fmaxf(mx, __shfl_xor(mx,32,64));
      mn = fminf(mn, __shfl_xor(mn,16,64)); mn = fminf(mn, __shfl_xor(mn,32,64));
      if (lane<16){
        int c = h*128 + wn*64+nt*16+lane;
        atomicAdd(&slots[(slot*256+c)*2+0], s);
        atomicAdd(&slots[(slot*256+c)*2+1], s2);
        size_t sidx = (size_t)mblk*2 + wm;
        maxv[sidx*256 + c] = mx;
        minv[sidx*256 + c] = mn;
      }
    }
  }
}

// ---------------------------------------------------------------------------
__global__ void stats_kernel(const float* __restrict__ slots, const float* __restrict__ g,
                             const float* __restrict__ beta, float* __restrict__ ssOut,
                             int C, float inv_cnt){
  int c = threadIdx.x;
  if (c >= C) return;
  float s=0.f, s2=0.f;
  for (int k=0;k<64;++k){
    s  += slots[(k*C + c)*2 + 0];
    s2 += slots[(k*C + c)*2 + 1];
  }
  float m = s * inv_cnt;
  float v = fmaxf(s2 * inv_cnt - m*m, 0.f);
  float sc = rsqrtf(v + 1e-5f) * g[c];
  ssOut[c] = sc;
  ssOut[C + c] = beta[c] - m*sc;
}

// ---------------------------------------------------------------------------
__global__ __launch_bounds__(256) void final_kernel(const float* __restrict__ minv,
                                                    const float* __restrict__ maxv,
                                                    const float* __restrict__ ss3,
                                                    float* __restrict__ out){
  __shared__ float tile[64][65];
  const int t = threadIdx.x;
  const int cb = blockIdx.x;
  const int sb = blockIdx.y;
  const int b  = blockIdx.z;
  const int w = t>>6, l = t&63;
  {
    int c = cb*64 + l;
    float sc = ss3[c], sh = ss3[256+c];
#pragma unroll
    for (int k=0;k<16;++k){
      int sl = k*4 + w;
      size_t mi = ((size_t)(b*1024 + sb*64 + sl))*256 + c;
      float v = (sc >= 0.f) ? maxv[mi] : minv[mi];
      tile[sl][l] = fmaxf(fmaf(v, sc, sh), 0.f);
    }
  }
  __syncthreads();
#pragma unroll
  for (int k=0;k<16;++k){
    int cl = k*4 + w;
    out[((size_t)(b*256 + cb*64 + cl))*1024 + sb*64 + l] = tile[l][cl];
  }
}

// ---------------------------------------------------------------------------
extern "C" void kernel_launch(void* const* d_in, const int* in_sizes, int n_in,
                              void* d_out, int out_size, void* d_ws, size_t ws_size,
                              hipStream_t stream){
  const float* xyz      = (const float*)d_in[0];
  const float* features = (const float*)d_in[1];
  const float* W1 = (const float*)d_in[2];
  const float* g1 = (const float*)d_in[3];
  const float* b1 = (const float*)d_in[4];
  const float* W2 = (const float*)d_in[5];
  const float* g2 = (const float*)d_in[6];
  const float* b2 = (const float*)d_in[7];
  const float* W3 = (const float*)d_in[8];
  const float* g3 = (const float*)d_in[9];
  const float* b3 = (const float*)d_in[10];
  float* out = (float*)d_out;

  char* ws = (char*)d_ws;
  size_t off = 0;
  auto alloc = [&](size_t bytes)->char*{
    char* p = ws + off;
    off = (off + bytes + 255) & ~(size_t)255;
    return p;
  };
  float* slots1 = (float*)alloc((size_t)64*128*2*4);
  float* slots2 = (float*)alloc((size_t)64*128*2*4);
  float* slots3 = (float*)alloc((size_t)64*256*2*4);
  float* ss1    = (float*)alloc(256*4);
  float* ss2    = (float*)alloc(256*4);
  float* ss3    = (float*)alloc(512*4);
  float* nxyz   = (float*)alloc((size_t)24576*4);
  int*   gi     = (int*)  alloc((size_t)M_*4);
  unsigned short* featT = (unsigned short*)alloc((size_t)B_*N_*CF_*2);
  unsigned short* Wt1   = (unsigned short*)alloc((size_t)128*160*2);
  unsigned short* Wt2   = (unsigned short*)alloc((size_t)128*128*2);
  unsigned short* Wt3   = (unsigned short*)alloc((size_t)256*128*2);
  float* minv = (float*)alloc((size_t)B_*S_*256*4);
  float* maxv = (float*)alloc((size_t)B_*S_*256*4);
  float* P    = (float*)alloc((size_t)B_*N_*128*4);   // 16.8 MB
  size_t base_end = off;
  unsigned short* y2 = (unsigned short*)alloc((size_t)M_*128*2);  // 134 MB
  const bool bigws = (off <= ws_size);   // constant across calls -> capture-safe
  (void)base_end;

  hipMemsetAsync(slots1, 0, (size_t)(64*128*2 + 64*128*2 + 64*256*2)*4, stream);

  prep_kernel<<<4160, 256, 0, stream>>>(features, W1, W2, W3, featT, Wt1, Wt2, Wt3);
  pgemm_kernel<<<256, 256, 0, stream>>>(featT, Wt1, P);
  fps_kernel<<<8, 256, 0, stream>>>(xyz, out, nxyz);
  qbp_y1_kernel<<<2048, 256, 0, stream>>>(xyz, nxyz, P, W1, gi, slots1);

  const float inv_cnt = 1.0f / (float)M_;
  stats_kernel<<<1, 128, 0, stream>>>(slots1, g1, b1, ss1, 128, inv_cnt);
  if (bigws){
    mm_fused<2,true><<<4096, 256, 0, stream>>>(P, W1, Wt2, Wt3, gi, xyz, nxyz,
                                               ss1, nullptr, slots2, nullptr, nullptr, y2);
    stats_kernel<<<1, 128, 0, stream>>>(slots2, g2, b2, ss2, 128, inv_cnt);
    mm3_kernel<<<4096, 256, 0, stream>>>(y2, Wt3, ss2, slots3, minv, maxv);
  } else {
    mm_fused<2,false><<<4096, 256, 0, stream>>>(P, W1, Wt2, Wt3, gi, xyz, nxyz,
                                                ss1, nullptr, slots2, nullptr, nullptr, nullptr);
    stats_kernel<<<1, 128, 0, stream>>>(slots2, g2, b2, ss2, 128, inv_cnt);
    mm_fused<3,false><<<4096, 256, 0, stream>>>(P, W1, Wt2, Wt3, gi, xyz, nxyz,
                                                ss1, ss2, slots3, minv, maxv, nullptr);
  }
  stats_kernel<<<1, 256, 0, stream>>>(slots3, g3, b3, ss3, 256, inv_cnt);
  final_kernel<<<dim3(4,16,8), 256, 0, stream>>>(minv, maxv, ss3, out + 24576);
}